// Round 1
// baseline (949.607 us; speedup 1.0000x reference)
//
#include <hip/hip_runtime.h>
#include <hip/hip_bf16.h>

// Problem constants (cheb_conv): B=16, N=50000, FIN=32, FOUT=32, K=6, NNZ=800000
#define NND   50000
#define NBATCH 16
#define NFIN  32
#define NFOUT 32
#define NCHEB 6
#define NNZE  800000
#define DDIM  512   // NBATCH*NFIN

typedef __attribute__((ext_vector_type(8))) short    short8;
typedef __attribute__((ext_vector_type(8))) unsigned short u16x8;
typedef __attribute__((ext_vector_type(4))) float    f32x4;

__device__ __forceinline__ float b2f(unsigned short u) {
  union { unsigned u; float f; } v; v.u = ((unsigned)u) << 16; return v.f;
}
__device__ __forceinline__ unsigned short f2bf(float f) {
  union { float f; unsigned u; } v; v.f = f;
  unsigned r = v.u + 0x7fffu + ((v.u >> 16) & 1u);   // RNE
  return (unsigned short)(r >> 16);
}

// ---------------- CSR build ----------------
__global__ void hist_kernel(const int* __restrict__ rows, int* __restrict__ cnt, int nnz) {
  int e = blockIdx.x * blockDim.x + threadIdx.x;
  if (e < nnz) atomicAdd(&cnt[rows[e]], 1);
}

// exclusive scan over cnt[0..n-1]; writes rowptr[0..n] and cursor[0..n-1]
__global__ void scan_kernel(const int* __restrict__ cnt, int* __restrict__ rowptr,
                            int* __restrict__ cursor, int n) {
  __shared__ int lds[1024];
  int tid = threadIdx.x;
  int run = 0;
  for (int base = 0; base <= n; base += 1024) {
    int i = base + tid;
    int v = (i < n) ? cnt[i] : 0;
    lds[tid] = v;
    __syncthreads();
    int s = v;
    for (int off = 1; off < 1024; off <<= 1) {
      int t = (tid >= off) ? lds[tid - off] : 0;
      __syncthreads();
      s += t;
      lds[tid] = s;
      __syncthreads();
    }
    int excl = run + s - v;
    if (i <= n) {
      rowptr[i] = excl;
      if (i < n) cursor[i] = excl;
    }
    run += lds[1023];
    __syncthreads();
  }
}

__global__ void fill_kernel(const int* __restrict__ rows, const int* __restrict__ cols,
                            const float* __restrict__ vals, int* __restrict__ cursor,
                            int* __restrict__ ccol, float* __restrict__ cval, int nnz) {
  int e = blockIdx.x * blockDim.x + threadIdx.x;
  if (e < nnz) {
    int r = rows[e];
    int p = atomicAdd(&cursor[r], 1);
    ccol[p] = cols[e];
    cval[p] = vals[e];
  }
}

// ---------------- Level 0: transpose x -> T0 (frag-ordered bf16), out = T0 @ W0 ----------------
// T layout per node: position p = lane*8 + j  <->  (b = lane&15, fi = (lane>>4)*8 + j)
// == MFMA 16x16x32 A-fragment order, so no shuffle is ever needed.
__global__ __launch_bounds__(256) void cheb_k0(const float* __restrict__ x,
                                               unsigned short* __restrict__ T0,
                                               const float* __restrict__ W,
                                               float* __restrict__ out) {
  int wave = threadIdx.x >> 6, lane = threadIdx.x & 63;
  int n = blockIdx.x * 4 + wave;
  int fo = lane & 15, kc = (lane >> 4) * 8;
  int b  = lane & 15;

  const float* xp = x + ((size_t)b * NND + n) * NFIN + kc;
  float4 xa = *(const float4*)xp;
  float4 xb = *(const float4*)(xp + 4);
  float tv[8] = {xa.x, xa.y, xa.z, xa.w, xb.x, xb.y, xb.z, xb.w};

  u16x8 tb;
#pragma unroll
  for (int j = 0; j < 8; ++j) tb[j] = f2bf(tv[j]);
  *(u16x8*)(T0 + (size_t)n * DDIM + lane * 8) = tb;

  short8 B0, B1;
#pragma unroll
  for (int j = 0; j < 8; ++j) {
    int fi = kc + j;
    const float* wp = W + ((size_t)fi * NCHEB + 0) * NFOUT + fo;
    B0[j] = (short)f2bf(wp[0]);
    B1[j] = (short)f2bf(wp[16]);
  }
  f32x4 c0 = {0.f, 0.f, 0.f, 0.f}, c1 = {0.f, 0.f, 0.f, 0.f};
  short8 a = __builtin_bit_cast(short8, tb);
  c0 = __builtin_amdgcn_mfma_f32_16x16x32_bf16(a, B0, c0, 0, 0, 0);
  c1 = __builtin_amdgcn_mfma_f32_16x16x32_bf16(a, B1, c1, 0, 0, 0);

  int br = (lane >> 4) * 4;
#pragma unroll
  for (int r = 0; r < 4; ++r) {
    size_t o = ((size_t)(br + r) * NND + n) * NFOUT + fo;
    out[o]      = c0[r];   // init (d_out is poisoned between replays)
    out[o + 16] = c1[r];
  }
}

// ---------------- Levels 1..5: T_k = alpha*spmm(T_{k-1}) - beta*T_{k-2} (in place), out += T_k @ W_k
__global__ __launch_bounds__(256) void cheb_level(const unsigned short* __restrict__ Tprev,
                                                  unsigned short* __restrict__ Tio,
                                                  const int* __restrict__ rowptr,
                                                  const int* __restrict__ ccol,
                                                  const float* __restrict__ cval,
                                                  const float* __restrict__ W,
                                                  float* __restrict__ out,
                                                  int kk, float alpha, float beta, int writeT) {
  int wave = threadIdx.x >> 6, lane = threadIdx.x & 63;
  int n = blockIdx.x * 4 + wave;
  int fo = lane & 15, kc = (lane >> 4) * 8;

  // W_k B-fragments (once per wave; L2-hot across blocks)
  short8 B0, B1;
#pragma unroll
  for (int j = 0; j < 8; ++j) {
    int fi = kc + j;
    const float* wp = W + ((size_t)fi * NCHEB + kk) * NFOUT + fo;
    B0[j] = (short)f2bf(wp[0]);
    B1[j] = (short)f2bf(wp[16]);
  }

  float acc[8] = {0.f, 0.f, 0.f, 0.f, 0.f, 0.f, 0.f, 0.f};
  int s = rowptr[n], e1 = rowptr[n + 1];
  const unsigned short* gbase = Tprev + lane * 8;

  int e = s;
  for (; e + 2 <= e1; e += 2) {           // 2-way unrolled gather for MLP
    int   ca = ccol[e],     cb = ccol[e + 1];
    float va = cval[e],     vb = cval[e + 1];
    u16x8 ta = *(const u16x8*)(gbase + (size_t)ca * DDIM);
    u16x8 tbv = *(const u16x8*)(gbase + (size_t)cb * DDIM);
#pragma unroll
    for (int j = 0; j < 8; ++j) {
      acc[j] = fmaf(va, b2f(ta[j]),  acc[j]);
      acc[j] = fmaf(vb, b2f(tbv[j]), acc[j]);
    }
  }
  if (e < e1) {
    int   ca = ccol[e];
    float va = cval[e];
    u16x8 ta = *(const u16x8*)(gbase + (size_t)ca * DDIM);
#pragma unroll
    for (int j = 0; j < 8; ++j) acc[j] = fmaf(va, b2f(ta[j]), acc[j]);
  }

  unsigned short* iop = Tio + (size_t)n * DDIM + lane * 8;
  float tk[8];
  if (beta != 0.f) {
    u16x8 tp2 = *(const u16x8*)iop;       // T_{k-2}, same position -> in-place safe
#pragma unroll
    for (int j = 0; j < 8; ++j) tk[j] = alpha * acc[j] - beta * b2f(tp2[j]);
  } else {
#pragma unroll
    for (int j = 0; j < 8; ++j) tk[j] = alpha * acc[j];
  }

  u16x8 tkb;
#pragma unroll
  for (int j = 0; j < 8; ++j) tkb[j] = f2bf(tk[j]);
  if (writeT) *(u16x8*)iop = tkb;

  f32x4 c0 = {0.f, 0.f, 0.f, 0.f}, c1 = {0.f, 0.f, 0.f, 0.f};
  short8 a = __builtin_bit_cast(short8, tkb);
  c0 = __builtin_amdgcn_mfma_f32_16x16x32_bf16(a, B0, c0, 0, 0, 0);
  c1 = __builtin_amdgcn_mfma_f32_16x16x32_bf16(a, B1, c1, 0, 0, 0);

  int br = (lane >> 4) * 4;
#pragma unroll
  for (int r = 0; r < 4; ++r) {
    size_t o = ((size_t)(br + r) * NND + n) * NFOUT + fo;
    out[o]      += c0[r];
    out[o + 16] += c1[r];
  }
}

// ---------------- launch ----------------
static inline size_t alignup(size_t v) { return (v + 255) & ~(size_t)255; }

extern "C" void kernel_launch(void* const* d_in, const int* in_sizes, int n_in,
                              void* d_out, int out_size, void* d_ws, size_t ws_size,
                              hipStream_t stream) {
  const float* x    = (const float*)d_in[0];
  const int*   rows = (const int*)d_in[1];
  const int*   cols = (const int*)d_in[2];
  const float* vals = (const float*)d_in[3];
  const float* W    = (const float*)d_in[4];
  float* out = (float*)d_out;

  char* p = (char*)d_ws;
  size_t off = 0;
  unsigned short* bufA = (unsigned short*)(p + off); off += alignup((size_t)NND * DDIM * 2);
  unsigned short* bufB = (unsigned short*)(p + off); off += alignup((size_t)NND * DDIM * 2);
  int*   cnt    = (int*)(p + off); off += alignup((size_t)NND * 4);
  int*   rowptr = (int*)(p + off); off += alignup((size_t)(NND + 1) * 4);
  int*   cursor = (int*)(p + off); off += alignup((size_t)NND * 4);
  int*   ccol   = (int*)(p + off); off += alignup((size_t)NNZE * 4);
  float* cval   = (float*)(p + off); off += alignup((size_t)NNZE * 4);

  hipMemsetAsync(cnt, 0, (size_t)NND * 4, stream);
  hist_kernel<<<(NNZE + 255) / 256, 256, 0, stream>>>(rows, cnt, NNZE);
  scan_kernel<<<1, 1024, 0, stream>>>(cnt, rowptr, cursor, NND);
  fill_kernel<<<(NNZE + 255) / 256, 256, 0, stream>>>(rows, cols, vals, cursor, ccol, cval, NNZE);

  const int grid = NND / 4;   // 12500 blocks x 256 threads, one wave per node
  cheb_k0<<<grid, 256, 0, stream>>>(x, bufA, W, out);
  cheb_level<<<grid, 256, 0, stream>>>(bufA, bufB, rowptr, ccol, cval, W, out, 1, 1.f, 0.f, 1);
  cheb_level<<<grid, 256, 0, stream>>>(bufB, bufA, rowptr, ccol, cval, W, out, 2, 2.f, 1.f, 1);
  cheb_level<<<grid, 256, 0, stream>>>(bufA, bufB, rowptr, ccol, cval, W, out, 3, 2.f, 1.f, 1);
  cheb_level<<<grid, 256, 0, stream>>>(bufB, bufA, rowptr, ccol, cval, W, out, 4, 2.f, 1.f, 1);
  cheb_level<<<grid, 256, 0, stream>>>(bufA, bufB, rowptr, ccol, cval, W, out, 5, 2.f, 1.f, 0);
}

// Round 2
// 909.149 us; speedup vs baseline: 1.0445x; 1.0445x over previous
//
#include <hip/hip_runtime.h>
#include <hip/hip_bf16.h>

// Problem constants (cheb_conv): B=16, N=50000, FIN=32, FOUT=32, K=6, NNZ=800000
#define NND   50000
#define NBATCH 16
#define NFIN  32
#define NFOUT 32
#define NCHEB 6
#define NNZE  800000
#define DDIM  512   // NBATCH*NFIN

typedef __attribute__((ext_vector_type(8))) short    short8;
typedef __attribute__((ext_vector_type(8))) unsigned short u16x8;
typedef __attribute__((ext_vector_type(4))) float    f32x4;

__device__ __forceinline__ float b2f(unsigned short u) {
  union { unsigned u; float f; } v; v.u = ((unsigned)u) << 16; return v.f;
}
__device__ __forceinline__ unsigned short f2bf(float f) {
  union { float f; unsigned u; } v; v.f = f;
  unsigned r = v.u + 0x7fffu + ((v.u >> 16) & 1u);   // RNE
  return (unsigned short)(r >> 16);
}

// ---------------- CSR build ----------------
__global__ void hist_kernel(const int* __restrict__ rows, int* __restrict__ cnt, int nnz) {
  int e = blockIdx.x * blockDim.x + threadIdx.x;
  if (e < nnz) atomicAdd(&cnt[rows[e]], 1);
}

__global__ void scan_kernel(const int* __restrict__ cnt, int* __restrict__ rowptr,
                            int* __restrict__ cursor, int n) {
  __shared__ int lds[1024];
  int tid = threadIdx.x;
  int run = 0;
  for (int base = 0; base <= n; base += 1024) {
    int i = base + tid;
    int v = (i < n) ? cnt[i] : 0;
    lds[tid] = v;
    __syncthreads();
    int s = v;
    for (int off = 1; off < 1024; off <<= 1) {
      int t = (tid >= off) ? lds[tid - off] : 0;
      __syncthreads();
      s += t;
      lds[tid] = s;
      __syncthreads();
    }
    int excl = run + s - v;
    if (i <= n) {
      rowptr[i] = excl;
      if (i < n) cursor[i] = excl;
    }
    run += lds[1023];
    __syncthreads();
  }
}

__global__ void fill_kernel(const int* __restrict__ rows, const int* __restrict__ cols,
                            const float* __restrict__ vals, int* __restrict__ cursor,
                            int* __restrict__ ccol, float* __restrict__ cval, int nnz) {
  int e = blockIdx.x * blockDim.x + threadIdx.x;
  if (e < nnz) {
    int r = rows[e];
    int p = atomicAdd(&cursor[r], 1);
    ccol[p] = cols[e];
    cval[p] = vals[e];
  }
}

// ---------------- W -> MFMA B-fragments (bf16), 12 frags (6 k x 2 fo-halves) ----------------
__global__ void wprep_kernel(const float* __restrict__ W, unsigned short* __restrict__ Wfrag) {
  int t = blockIdx.x * blockDim.x + threadIdx.x;
  if (t >= 12 * 64) return;
  int frag = t >> 6, lane = t & 63;
  int kk = frag >> 1, h = frag & 1;
  int fo = (lane & 15) + h * 16, kc = (lane >> 4) * 8;
  u16x8 b;
#pragma unroll
  for (int j = 0; j < 8; ++j)
    b[j] = f2bf(W[((size_t)(kc + j) * NCHEB + kk) * NFOUT + fo]);
  *(u16x8*)(Wfrag + (size_t)t * 8) = b;
}

// ---------------- Level 0 (deferred): transpose x -> T0 only ----------------
// T layout per node: position p = lane*8 + j <-> (b = lane&15, fi = (lane>>4)*8 + j)
// == MFMA 16x16x32 A-fragment order.
__global__ __launch_bounds__(256) void cheb_k0_nf(const float* __restrict__ x,
                                                  unsigned short* __restrict__ T0) {
  int wave = threadIdx.x >> 6, lane = threadIdx.x & 63;
  int n = blockIdx.x * 4 + wave;
  int kc = (lane >> 4) * 8;
  int b  = lane & 15;

  const float* xp = x + ((size_t)b * NND + n) * NFIN + kc;
  float4 xa = *(const float4*)xp;
  float4 xb = *(const float4*)(xp + 4);
  float tv[8] = {xa.x, xa.y, xa.z, xa.w, xb.x, xb.y, xb.z, xb.w};

  u16x8 tb;
#pragma unroll
  for (int j = 0; j < 8; ++j) tb[j] = f2bf(tv[j]);
  *(u16x8*)(T0 + (size_t)n * DDIM + lane * 8) = tb;
}

// ---------------- Levels 1..5 (deferred): T_k = alpha*spmm(T_{k-1}) - beta*T_{k-2} ----------------
__global__ __launch_bounds__(256) void cheb_level_nf(const unsigned short* __restrict__ Tprev,
                                                     const unsigned short* __restrict__ Tpp,
                                                     unsigned short* __restrict__ Tdst,
                                                     const int* __restrict__ rowptr,
                                                     const int* __restrict__ ccol,
                                                     const float* __restrict__ cval,
                                                     float alpha, float beta) {
  int wave = threadIdx.x >> 6, lane = threadIdx.x & 63;
  int n = blockIdx.x * 4 + wave;

  float acc[8] = {0.f, 0.f, 0.f, 0.f, 0.f, 0.f, 0.f, 0.f};
  int s = rowptr[n], e1 = rowptr[n + 1];
  const unsigned short* gbase = Tprev + lane * 8;

  int e = s;
  for (; e + 4 <= e1; e += 4) {           // 4-way unrolled gather for MLP
    int c0i = __builtin_nontemporal_load(ccol + e);
    int c1i = __builtin_nontemporal_load(ccol + e + 1);
    int c2i = __builtin_nontemporal_load(ccol + e + 2);
    int c3i = __builtin_nontemporal_load(ccol + e + 3);
    float v0 = __builtin_nontemporal_load(cval + e);
    float v1 = __builtin_nontemporal_load(cval + e + 1);
    float v2 = __builtin_nontemporal_load(cval + e + 2);
    float v3 = __builtin_nontemporal_load(cval + e + 3);
    u16x8 t0 = *(const u16x8*)(gbase + (size_t)c0i * DDIM);
    u16x8 t1 = *(const u16x8*)(gbase + (size_t)c1i * DDIM);
    u16x8 t2 = *(const u16x8*)(gbase + (size_t)c2i * DDIM);
    u16x8 t3 = *(const u16x8*)(gbase + (size_t)c3i * DDIM);
#pragma unroll
    for (int j = 0; j < 8; ++j) {
      acc[j] = fmaf(v0, b2f(t0[j]), acc[j]);
      acc[j] = fmaf(v1, b2f(t1[j]), acc[j]);
      acc[j] = fmaf(v2, b2f(t2[j]), acc[j]);
      acc[j] = fmaf(v3, b2f(t3[j]), acc[j]);
    }
  }
  for (; e < e1; ++e) {
    int   ci = __builtin_nontemporal_load(ccol + e);
    float vi = __builtin_nontemporal_load(cval + e);
    u16x8 ti = *(const u16x8*)(gbase + (size_t)ci * DDIM);
#pragma unroll
    for (int j = 0; j < 8; ++j) acc[j] = fmaf(vi, b2f(ti[j]), acc[j]);
  }

  size_t rowoff = (size_t)n * DDIM + lane * 8;
  float tk[8];
  if (beta != 0.f) {
    u16x8 tp2 = *(const u16x8*)(Tpp + rowoff);
#pragma unroll
    for (int j = 0; j < 8; ++j) tk[j] = alpha * acc[j] - beta * b2f(tp2[j]);
  } else {
#pragma unroll
    for (int j = 0; j < 8; ++j) tk[j] = alpha * acc[j];
  }

  u16x8 tkb;
#pragma unroll
  for (int j = 0; j < 8; ++j) tkb[j] = f2bf(tk[j]);
  *(u16x8*)(Tdst + rowoff) = tkb;
}

// ---------------- Epilogue: out[b][n][fo] = sum_k T_k[n] @ W_k ----------------
__global__ __launch_bounds__(256) void cheb_epilogue(const unsigned short* __restrict__ T,
                                                     const unsigned short* __restrict__ Wfrag,
                                                     float* __restrict__ out) {
  int wave = threadIdx.x >> 6, lane = threadIdx.x & 63;
  int n = blockIdx.x * 4 + wave;
  int fo = lane & 15;

  f32x4 c0 = {0.f, 0.f, 0.f, 0.f}, c1 = {0.f, 0.f, 0.f, 0.f};
#pragma unroll
  for (int kk = 0; kk < NCHEB; ++kk) {
    short8 a  = *(const short8*)(T + ((size_t)kk * NND + n) * DDIM + lane * 8);
    short8 B0 = *(const short8*)(Wfrag + ((size_t)(kk * 2 + 0) * 64 + lane) * 8);
    short8 B1 = *(const short8*)(Wfrag + ((size_t)(kk * 2 + 1) * 64 + lane) * 8);
    c0 = __builtin_amdgcn_mfma_f32_16x16x32_bf16(a, B0, c0, 0, 0, 0);
    c1 = __builtin_amdgcn_mfma_f32_16x16x32_bf16(a, B1, c1, 0, 0, 0);
  }
  int br = (lane >> 4) * 4;
#pragma unroll
  for (int r = 0; r < 4; ++r) {
    size_t o = ((size_t)(br + r) * NND + n) * NFOUT + fo;
    out[o]      = c0[r];
    out[o + 16] = c1[r];
  }
}

// ================= Fallback (fused epilogue, 2-buffer ping-pong) =================
__global__ __launch_bounds__(256) void cheb_k0_fused(const float* __restrict__ x,
                                                     unsigned short* __restrict__ T0,
                                                     const float* __restrict__ W,
                                                     float* __restrict__ out) {
  int wave = threadIdx.x >> 6, lane = threadIdx.x & 63;
  int n = blockIdx.x * 4 + wave;
  int fo = lane & 15, kc = (lane >> 4) * 8;
  int b  = lane & 15;

  const float* xp = x + ((size_t)b * NND + n) * NFIN + kc;
  float4 xa = *(const float4*)xp;
  float4 xb = *(const float4*)(xp + 4);
  float tv[8] = {xa.x, xa.y, xa.z, xa.w, xb.x, xb.y, xb.z, xb.w};

  u16x8 tb;
#pragma unroll
  for (int j = 0; j < 8; ++j) tb[j] = f2bf(tv[j]);
  *(u16x8*)(T0 + (size_t)n * DDIM + lane * 8) = tb;

  short8 B0, B1;
#pragma unroll
  for (int j = 0; j < 8; ++j) {
    int fi = kc + j;
    const float* wp = W + ((size_t)fi * NCHEB + 0) * NFOUT + fo;
    B0[j] = (short)f2bf(wp[0]);
    B1[j] = (short)f2bf(wp[16]);
  }
  f32x4 c0 = {0.f, 0.f, 0.f, 0.f}, c1 = {0.f, 0.f, 0.f, 0.f};
  short8 a = __builtin_bit_cast(short8, tb);
  c0 = __builtin_amdgcn_mfma_f32_16x16x32_bf16(a, B0, c0, 0, 0, 0);
  c1 = __builtin_amdgcn_mfma_f32_16x16x32_bf16(a, B1, c1, 0, 0, 0);

  int br = (lane >> 4) * 4;
#pragma unroll
  for (int r = 0; r < 4; ++r) {
    size_t o = ((size_t)(br + r) * NND + n) * NFOUT + fo;
    out[o]      = c0[r];
    out[o + 16] = c1[r];
  }
}

__global__ __launch_bounds__(256) void cheb_level_fused(const unsigned short* __restrict__ Tprev,
                                                        unsigned short* __restrict__ Tio,
                                                        const int* __restrict__ rowptr,
                                                        const int* __restrict__ ccol,
                                                        const float* __restrict__ cval,
                                                        const float* __restrict__ W,
                                                        float* __restrict__ out,
                                                        int kk, float alpha, float beta, int writeT) {
  int wave = threadIdx.x >> 6, lane = threadIdx.x & 63;
  int n = blockIdx.x * 4 + wave;
  int fo = lane & 15, kc = (lane >> 4) * 8;

  short8 B0, B1;
#pragma unroll
  for (int j = 0; j < 8; ++j) {
    int fi = kc + j;
    const float* wp = W + ((size_t)fi * NCHEB + kk) * NFOUT + fo;
    B0[j] = (short)f2bf(wp[0]);
    B1[j] = (short)f2bf(wp[16]);
  }

  float acc[8] = {0.f, 0.f, 0.f, 0.f, 0.f, 0.f, 0.f, 0.f};
  int s = rowptr[n], e1 = rowptr[n + 1];
  const unsigned short* gbase = Tprev + lane * 8;

  int e = s;
  for (; e + 2 <= e1; e += 2) {
    int   ca = ccol[e],     cb = ccol[e + 1];
    float va = cval[e],     vb = cval[e + 1];
    u16x8 ta = *(const u16x8*)(gbase + (size_t)ca * DDIM);
    u16x8 tbv = *(const u16x8*)(gbase + (size_t)cb * DDIM);
#pragma unroll
    for (int j = 0; j < 8; ++j) {
      acc[j] = fmaf(va, b2f(ta[j]),  acc[j]);
      acc[j] = fmaf(vb, b2f(tbv[j]), acc[j]);
    }
  }
  if (e < e1) {
    int   ca = ccol[e];
    float va = cval[e];
    u16x8 ta = *(const u16x8*)(gbase + (size_t)ca * DDIM);
#pragma unroll
    for (int j = 0; j < 8; ++j) acc[j] = fmaf(va, b2f(ta[j]), acc[j]);
  }

  unsigned short* iop = Tio + (size_t)n * DDIM + lane * 8;
  float tk[8];
  if (beta != 0.f) {
    u16x8 tp2 = *(const u16x8*)iop;
#pragma unroll
    for (int j = 0; j < 8; ++j) tk[j] = alpha * acc[j] - beta * b2f(tp2[j]);
  } else {
#pragma unroll
    for (int j = 0; j < 8; ++j) tk[j] = alpha * acc[j];
  }

  u16x8 tkb;
#pragma unroll
  for (int j = 0; j < 8; ++j) tkb[j] = f2bf(tk[j]);
  if (writeT) *(u16x8*)iop = tkb;

  f32x4 c0 = {0.f, 0.f, 0.f, 0.f}, c1 = {0.f, 0.f, 0.f, 0.f};
  short8 a = __builtin_bit_cast(short8, tkb);
  c0 = __builtin_amdgcn_mfma_f32_16x16x32_bf16(a, B0, c0, 0, 0, 0);
  c1 = __builtin_amdgcn_mfma_f32_16x16x32_bf16(a, B1, c1, 0, 0, 0);

  int br = (lane >> 4) * 4;
#pragma unroll
  for (int r = 0; r < 4; ++r) {
    size_t o = ((size_t)(br + r) * NND + n) * NFOUT + fo;
    out[o]      += c0[r];
    out[o + 16] += c1[r];
  }
}

// ---------------- launch ----------------
static inline size_t alignup(size_t v) { return (v + 255) & ~(size_t)255; }

extern "C" void kernel_launch(void* const* d_in, const int* in_sizes, int n_in,
                              void* d_out, int out_size, void* d_ws, size_t ws_size,
                              hipStream_t stream) {
  const float* x    = (const float*)d_in[0];
  const int*   rows = (const int*)d_in[1];
  const int*   cols = (const int*)d_in[2];
  const float* vals = (const float*)d_in[3];
  const float* W    = (const float*)d_in[4];
  float* out = (float*)d_out;

  const size_t tbytes   = alignup((size_t)NND * DDIM * 2);       // one T level
  const size_t csrbytes = 3 * alignup((size_t)(NND + 1) * 4)
                        + 2 * alignup((size_t)NNZE * 4);
  const size_t deferred_need = (size_t)NCHEB * tbytes + alignup(12 * 64 * 8 * 2) + csrbytes;

  const int grid = NND / 4;   // 12500 blocks x 256 threads, one wave per node

  if (ws_size >= deferred_need) {
    // ---------- deferred-epilogue path ----------
    char* p = (char*)d_ws;
    size_t off = 0;
    unsigned short* Tall  = (unsigned short*)(p + off); off += (size_t)NCHEB * tbytes;
    unsigned short* Wfrag = (unsigned short*)(p + off); off += alignup(12 * 64 * 8 * 2);
    int*   cnt    = (int*)(p + off); off += alignup((size_t)(NND + 1) * 4);
    int*   rowptr = (int*)(p + off); off += alignup((size_t)(NND + 1) * 4);
    int*   cursor = (int*)(p + off); off += alignup((size_t)(NND + 1) * 4);
    int*   ccol   = (int*)(p + off); off += alignup((size_t)NNZE * 4);
    float* cval   = (float*)(p + off); off += alignup((size_t)NNZE * 4);

    hipMemsetAsync(cnt, 0, (size_t)NND * 4, stream);
    hist_kernel<<<(NNZE + 255) / 256, 256, 0, stream>>>(rows, cnt, NNZE);
    scan_kernel<<<1, 1024, 0, stream>>>(cnt, rowptr, cursor, NND);
    fill_kernel<<<(NNZE + 255) / 256, 256, 0, stream>>>(rows, cols, vals, cursor, ccol, cval, NNZE);
    wprep_kernel<<<3, 256, 0, stream>>>(W, Wfrag);

    auto Tk = [&](int k) { return Tall + (size_t)k * NND * DDIM; };

    cheb_k0_nf<<<grid, 256, 0, stream>>>(x, Tk(0));
    cheb_level_nf<<<grid, 256, 0, stream>>>(Tk(0), nullptr, Tk(1), rowptr, ccol, cval, 1.f, 0.f);
    cheb_level_nf<<<grid, 256, 0, stream>>>(Tk(1), Tk(0), Tk(2), rowptr, ccol, cval, 2.f, 1.f);
    cheb_level_nf<<<grid, 256, 0, stream>>>(Tk(2), Tk(1), Tk(3), rowptr, ccol, cval, 2.f, 1.f);
    cheb_level_nf<<<grid, 256, 0, stream>>>(Tk(3), Tk(2), Tk(4), rowptr, ccol, cval, 2.f, 1.f);
    cheb_level_nf<<<grid, 256, 0, stream>>>(Tk(4), Tk(3), Tk(5), rowptr, ccol, cval, 2.f, 1.f);
    cheb_epilogue<<<grid, 256, 0, stream>>>(Tall, Wfrag, out);
  } else {
    // ---------- fallback: fused epilogue, 2 T buffers ----------
    char* p = (char*)d_ws;
    size_t off = 0;
    unsigned short* bufA = (unsigned short*)(p + off); off += tbytes;
    unsigned short* bufB = (unsigned short*)(p + off); off += tbytes;
    int*   cnt    = (int*)(p + off); off += alignup((size_t)(NND + 1) * 4);
    int*   rowptr = (int*)(p + off); off += alignup((size_t)(NND + 1) * 4);
    int*   cursor = (int*)(p + off); off += alignup((size_t)(NND + 1) * 4);
    int*   ccol   = (int*)(p + off); off += alignup((size_t)NNZE * 4);
    float* cval   = (float*)(p + off); off += alignup((size_t)NNZE * 4);

    hipMemsetAsync(cnt, 0, (size_t)NND * 4, stream);
    hist_kernel<<<(NNZE + 255) / 256, 256, 0, stream>>>(rows, cnt, NNZE);
    scan_kernel<<<1, 1024, 0, stream>>>(cnt, rowptr, cursor, NND);
    fill_kernel<<<(NNZE + 255) / 256, 256, 0, stream>>>(rows, cols, vals, cursor, ccol, cval, NNZE);

    cheb_k0_fused<<<grid, 256, 0, stream>>>(x, bufA, W, out);
    cheb_level_fused<<<grid, 256, 0, stream>>>(bufA, bufB, rowptr, ccol, cval, W, out, 1, 1.f, 0.f, 1);
    cheb_level_fused<<<grid, 256, 0, stream>>>(bufB, bufA, rowptr, ccol, cval, W, out, 2, 2.f, 1.f, 1);
    cheb_level_fused<<<grid, 256, 0, stream>>>(bufA, bufB, rowptr, ccol, cval, W, out, 3, 2.f, 1.f, 1);
    cheb_level_fused<<<grid, 256, 0, stream>>>(bufB, bufA, rowptr, ccol, cval, W, out, 4, 2.f, 1.f, 1);
    cheb_level_fused<<<grid, 256, 0, stream>>>(bufA, bufB, rowptr, ccol, cval, W, out, 5, 2.f, 1.f, 0);
  }
}

// Round 3
// 785.689 us; speedup vs baseline: 1.2086x; 1.1571x over previous
//
#include <hip/hip_runtime.h>
#include <hip/hip_bf16.h>

// Problem constants (cheb_conv): B=16, N=50000, FIN=32, FOUT=32, K=6, NNZ=800000
#define NND   50000
#define NBATCH 16
#define NFIN  32
#define NFOUT 32
#define NCHEB 6
#define NNZE  800000
#define DDIM  512   // NBATCH*NFIN

typedef __attribute__((ext_vector_type(8))) short    short8;
typedef __attribute__((ext_vector_type(8))) unsigned short u16x8;
typedef __attribute__((ext_vector_type(4))) float    f32x4;

__device__ __forceinline__ float b2f(unsigned short u) {
  union { unsigned u; float f; } v; v.u = ((unsigned)u) << 16; return v.f;
}
__device__ __forceinline__ unsigned short f2bf(float f) {
  union { float f; unsigned u; } v; v.f = f;
  unsigned r = v.u + 0x7fffu + ((v.u >> 16) & 1u);   // RNE
  return (unsigned short)(r >> 16);
}

// ---------------- CSR build ----------------
__global__ void hist_kernel(const int* __restrict__ rows, int* __restrict__ cnt, int nnz) {
  int e = blockIdx.x * blockDim.x + threadIdx.x;
  if (e < nnz) atomicAdd(&cnt[rows[e]], 1);
}

// hierarchical scan: A (block-local) -> B (partials, serial tiny) -> C (add offsets)
__global__ __launch_bounds__(1024) void scanA_kernel(const int* __restrict__ cnt,
                                                     int* __restrict__ rowptr,
                                                     int* __restrict__ partials, int n) {
  __shared__ int lds[1024];
  int b = blockIdx.x, tid = threadIdx.x, i = b * 1024 + tid;
  int v = (i < n) ? cnt[i] : 0;
  lds[tid] = v;
  __syncthreads();
  int s = v;
  for (int off = 1; off < 1024; off <<= 1) {
    int t = (tid >= off) ? lds[tid - off] : 0;
    __syncthreads();
    s += t;
    lds[tid] = s;
    __syncthreads();
  }
  if (i < n) rowptr[i] = s - v;          // local exclusive
  if (tid == 1023) partials[b] = s;      // block sum
}

__global__ void scanB_kernel(int* __restrict__ partials, int nb) {
  int run = 0;
  for (int b = 0; b < nb; ++b) { int t = partials[b]; partials[b] = run; run += t; }
}

__global__ __launch_bounds__(1024) void scanC_kernel(const int* __restrict__ partials,
                                                     int* __restrict__ rowptr,
                                                     int* __restrict__ cursor, int n) {
  int i = blockIdx.x * 1024 + threadIdx.x;
  if (i < n) {
    int r = rowptr[i] + partials[blockIdx.x];
    rowptr[i] = r;
    cursor[i] = r;
  }
  if (i == n) rowptr[n] = NNZE;
}

__global__ void fill_kernel(const int* __restrict__ rows, const int* __restrict__ cols,
                            const float* __restrict__ vals, int* __restrict__ cursor,
                            int* __restrict__ ccol, float* __restrict__ cval, int nnz) {
  int e = blockIdx.x * blockDim.x + threadIdx.x;
  if (e < nnz) {
    int r = rows[e];
    int p = atomicAdd(&cursor[r], 1);
    ccol[p] = cols[e];
    cval[p] = vals[e];
  }
}

// ---------------- W -> MFMA B-fragments (bf16), 12 frags (6 k x 2 fo-halves) ----------------
__global__ void wprep_kernel(const float* __restrict__ W, unsigned short* __restrict__ Wfrag) {
  int t = blockIdx.x * blockDim.x + threadIdx.x;
  if (t >= 12 * 64) return;
  int frag = t >> 6, lane = t & 63;
  int kk = frag >> 1, h = frag & 1;
  int fo = (lane & 15) + h * 16, kc = (lane >> 4) * 8;
  u16x8 b;
#pragma unroll
  for (int j = 0; j < 8; ++j)
    b[j] = f2bf(W[((size_t)(kc + j) * NCHEB + kk) * NFOUT + fo]);
  *(u16x8*)(Wfrag + (size_t)t * 8) = b;
}

// ---------------- Level 0: transpose x -> T0 (MFMA A-frag order) ----------------
// T layout per node: position p = lane*8 + j <-> (b = lane&15, fi = (lane>>4)*8 + j)
__global__ __launch_bounds__(256) void cheb_k0_nf(const float* __restrict__ x,
                                                  unsigned short* __restrict__ T0) {
  int wave = threadIdx.x >> 6, lane = threadIdx.x & 63;
  int n = blockIdx.x * 4 + wave;
  int kc = (lane >> 4) * 8;
  int b  = lane & 15;

  const float* xp = x + ((size_t)b * NND + n) * NFIN + kc;
  float4 xa = *(const float4*)xp;
  float4 xb = *(const float4*)(xp + 4);
  float tv[8] = {xa.x, xa.y, xa.z, xa.w, xb.x, xb.y, xb.z, xb.w};

  u16x8 tb;
#pragma unroll
  for (int j = 0; j < 8; ++j) tb[j] = f2bf(tv[j]);
  *(u16x8*)(T0 + (size_t)n * DDIM + lane * 8) = tb;
}

// ---------------- gather core: acc += sum_e val[e] * Tprev[col[e]] (8-deep MLP) ----------------
__device__ __forceinline__ void gather_row(const unsigned short* __restrict__ gbase,
                                           const int* __restrict__ ccol,
                                           const float* __restrict__ cval,
                                           int s, int e1, float acc[8]) {
  int e = s;
  for (; e + 8 <= e1; e += 8) {
    int c[8]; float v[8];
#pragma unroll
    for (int q = 0; q < 8; ++q) {
      c[q] = __builtin_nontemporal_load(ccol + e + q);
      v[q] = __builtin_nontemporal_load(cval + e + q);
    }
    u16x8 t[8];
#pragma unroll
    for (int q = 0; q < 8; ++q) t[q] = *(const u16x8*)(gbase + (size_t)c[q] * DDIM);
#pragma unroll
    for (int q = 0; q < 8; ++q)
#pragma unroll
      for (int j = 0; j < 8; ++j) acc[j] = fmaf(v[q], b2f(t[q][j]), acc[j]);
  }
  if (e + 4 <= e1) {
    int c[4]; float v[4];
#pragma unroll
    for (int q = 0; q < 4; ++q) {
      c[q] = __builtin_nontemporal_load(ccol + e + q);
      v[q] = __builtin_nontemporal_load(cval + e + q);
    }
    u16x8 t[4];
#pragma unroll
    for (int q = 0; q < 4; ++q) t[q] = *(const u16x8*)(gbase + (size_t)c[q] * DDIM);
#pragma unroll
    for (int q = 0; q < 4; ++q)
#pragma unroll
      for (int j = 0; j < 8; ++j) acc[j] = fmaf(v[q], b2f(t[q][j]), acc[j]);
    e += 4;
  }
  for (; e < e1; ++e) {
    int   ci = __builtin_nontemporal_load(ccol + e);
    float vi = __builtin_nontemporal_load(cval + e);
    u16x8 ti = *(const u16x8*)(gbase + (size_t)ci * DDIM);
#pragma unroll
    for (int j = 0; j < 8; ++j) acc[j] = fmaf(vi, b2f(ti[j]), acc[j]);
  }
}

// ---------------- Levels 1..4: T_k = alpha*spmm(T_{k-1}) - beta*T_{k-2} ----------------
__global__ __launch_bounds__(256) void cheb_level_v3(const unsigned short* __restrict__ Tprev,
                                                     const unsigned short* __restrict__ Tpp,
                                                     unsigned short* __restrict__ Tdst,
                                                     const int* __restrict__ rowptr,
                                                     const int* __restrict__ ccol,
                                                     const float* __restrict__ cval,
                                                     float alpha, float beta) {
  int wave = threadIdx.x >> 6, lane = threadIdx.x & 63;
  int n = blockIdx.x * 4 + wave;
  int s = rowptr[n], e1 = rowptr[n + 1];
  size_t rowoff = (size_t)n * DDIM + lane * 8;

  u16x8 tp2 = {};                         // early independent load (in flight during gather)
  if (beta != 0.f) tp2 = *(const u16x8*)(Tpp + rowoff);

  float acc[8] = {0.f, 0.f, 0.f, 0.f, 0.f, 0.f, 0.f, 0.f};
  gather_row(Tprev + lane * 8, ccol, cval, s, e1, acc);

  float tk[8];
  if (beta != 0.f) {
#pragma unroll
    for (int j = 0; j < 8; ++j) tk[j] = alpha * acc[j] - beta * b2f(tp2[j]);
  } else {
#pragma unroll
    for (int j = 0; j < 8; ++j) tk[j] = alpha * acc[j];
  }

  u16x8 tkb;
#pragma unroll
  for (int j = 0; j < 8; ++j) tkb[j] = f2bf(tk[j]);
  *(u16x8*)(Tdst + rowoff) = tkb;
}

// ---------------- Level 5 fused with epilogue: T5 stays in regs; out = sum_k T_k @ W_k ----------------
__global__ __launch_bounds__(256) void cheb_level5_epi(const unsigned short* __restrict__ T4,
                                                       const unsigned short* __restrict__ T3,
                                                       const unsigned short* __restrict__ Tall,
                                                       const unsigned short* __restrict__ Wfrag,
                                                       const int* __restrict__ rowptr,
                                                       const int* __restrict__ ccol,
                                                       const float* __restrict__ cval,
                                                       float* __restrict__ out) {
  int wave = threadIdx.x >> 6, lane = threadIdx.x & 63;
  int n = blockIdx.x * 4 + wave;
  int s = rowptr[n], e1 = rowptr[n + 1];
  size_t rowoff = (size_t)n * DDIM + lane * 8;

  u16x8 tp2 = *(const u16x8*)(T3 + rowoff);

  float acc[8] = {0.f, 0.f, 0.f, 0.f, 0.f, 0.f, 0.f, 0.f};
  gather_row(T4 + lane * 8, ccol, cval, s, e1, acc);

  u16x8 t5b;
#pragma unroll
  for (int j = 0; j < 8; ++j) t5b[j] = f2bf(2.f * acc[j] - b2f(tp2[j]));

  int fo = lane & 15;
  f32x4 c0 = {0.f, 0.f, 0.f, 0.f}, c1 = {0.f, 0.f, 0.f, 0.f};
#pragma unroll
  for (int kk = 0; kk < 5; ++kk) {
    short8 a  = *(const short8*)(Tall + (size_t)kk * NND * DDIM + rowoff);
    short8 B0 = *(const short8*)(Wfrag + ((size_t)(kk * 2 + 0) * 64 + lane) * 8);
    short8 B1 = *(const short8*)(Wfrag + ((size_t)(kk * 2 + 1) * 64 + lane) * 8);
    c0 = __builtin_amdgcn_mfma_f32_16x16x32_bf16(a, B0, c0, 0, 0, 0);
    c1 = __builtin_amdgcn_mfma_f32_16x16x32_bf16(a, B1, c1, 0, 0, 0);
  }
  {
    short8 a5 = __builtin_bit_cast(short8, t5b);
    short8 B0 = *(const short8*)(Wfrag + ((size_t)(5 * 2 + 0) * 64 + lane) * 8);
    short8 B1 = *(const short8*)(Wfrag + ((size_t)(5 * 2 + 1) * 64 + lane) * 8);
    c0 = __builtin_amdgcn_mfma_f32_16x16x32_bf16(a5, B0, c0, 0, 0, 0);
    c1 = __builtin_amdgcn_mfma_f32_16x16x32_bf16(a5, B1, c1, 0, 0, 0);
  }

  int br = (lane >> 4) * 4;
#pragma unroll
  for (int r = 0; r < 4; ++r) {
    size_t o = ((size_t)(br + r) * NND + n) * NFOUT + fo;
    out[o]      = c0[r];
    out[o + 16] = c1[r];
  }
}

// ================= Fallback (fused epilogue, 2-buffer ping-pong) =================
__global__ void scan_kernel(const int* __restrict__ cnt, int* __restrict__ rowptr,
                            int* __restrict__ cursor, int n) {
  __shared__ int lds[1024];
  int tid = threadIdx.x;
  int run = 0;
  for (int base = 0; base <= n; base += 1024) {
    int i = base + tid;
    int v = (i < n) ? cnt[i] : 0;
    lds[tid] = v;
    __syncthreads();
    int s = v;
    for (int off = 1; off < 1024; off <<= 1) {
      int t = (tid >= off) ? lds[tid - off] : 0;
      __syncthreads();
      s += t;
      lds[tid] = s;
      __syncthreads();
    }
    int excl = run + s - v;
    if (i <= n) {
      rowptr[i] = excl;
      if (i < n) cursor[i] = excl;
    }
    run += lds[1023];
    __syncthreads();
  }
}

__global__ __launch_bounds__(256) void cheb_k0_fused(const float* __restrict__ x,
                                                     unsigned short* __restrict__ T0,
                                                     const float* __restrict__ W,
                                                     float* __restrict__ out) {
  int wave = threadIdx.x >> 6, lane = threadIdx.x & 63;
  int n = blockIdx.x * 4 + wave;
  int fo = lane & 15, kc = (lane >> 4) * 8;
  int b  = lane & 15;

  const float* xp = x + ((size_t)b * NND + n) * NFIN + kc;
  float4 xa = *(const float4*)xp;
  float4 xb = *(const float4*)(xp + 4);
  float tv[8] = {xa.x, xa.y, xa.z, xa.w, xb.x, xb.y, xb.z, xb.w};

  u16x8 tb;
#pragma unroll
  for (int j = 0; j < 8; ++j) tb[j] = f2bf(tv[j]);
  *(u16x8*)(T0 + (size_t)n * DDIM + lane * 8) = tb;

  short8 B0, B1;
#pragma unroll
  for (int j = 0; j < 8; ++j) {
    int fi = kc + j;
    const float* wp = W + ((size_t)fi * NCHEB + 0) * NFOUT + fo;
    B0[j] = (short)f2bf(wp[0]);
    B1[j] = (short)f2bf(wp[16]);
  }
  f32x4 c0 = {0.f, 0.f, 0.f, 0.f}, c1 = {0.f, 0.f, 0.f, 0.f};
  short8 a = __builtin_bit_cast(short8, tb);
  c0 = __builtin_amdgcn_mfma_f32_16x16x32_bf16(a, B0, c0, 0, 0, 0);
  c1 = __builtin_amdgcn_mfma_f32_16x16x32_bf16(a, B1, c1, 0, 0, 0);

  int br = (lane >> 4) * 4;
#pragma unroll
  for (int r = 0; r < 4; ++r) {
    size_t o = ((size_t)(br + r) * NND + n) * NFOUT + fo;
    out[o]      = c0[r];
    out[o + 16] = c1[r];
  }
}

__global__ __launch_bounds__(256) void cheb_level_fused(const unsigned short* __restrict__ Tprev,
                                                        unsigned short* __restrict__ Tio,
                                                        const int* __restrict__ rowptr,
                                                        const int* __restrict__ ccol,
                                                        const float* __restrict__ cval,
                                                        const float* __restrict__ W,
                                                        float* __restrict__ out,
                                                        int kk, float alpha, float beta, int writeT) {
  int wave = threadIdx.x >> 6, lane = threadIdx.x & 63;
  int n = blockIdx.x * 4 + wave;
  int fo = lane & 15, kc = (lane >> 4) * 8;

  short8 B0, B1;
#pragma unroll
  for (int j = 0; j < 8; ++j) {
    int fi = kc + j;
    const float* wp = W + ((size_t)fi * NCHEB + kk) * NFOUT + fo;
    B0[j] = (short)f2bf(wp[0]);
    B1[j] = (short)f2bf(wp[16]);
  }

  float acc[8] = {0.f, 0.f, 0.f, 0.f, 0.f, 0.f, 0.f, 0.f};
  int s = rowptr[n], e1 = rowptr[n + 1];
  gather_row(Tprev + lane * 8, ccol, cval, s, e1, acc);

  unsigned short* iop = Tio + (size_t)n * DDIM + lane * 8;
  float tk[8];
  if (beta != 0.f) {
    u16x8 tp2 = *(const u16x8*)iop;
#pragma unroll
    for (int j = 0; j < 8; ++j) tk[j] = alpha * acc[j] - beta * b2f(tp2[j]);
  } else {
#pragma unroll
    for (int j = 0; j < 8; ++j) tk[j] = alpha * acc[j];
  }

  u16x8 tkb;
#pragma unroll
  for (int j = 0; j < 8; ++j) tkb[j] = f2bf(tk[j]);
  if (writeT) *(u16x8*)iop = tkb;

  f32x4 c0 = {0.f, 0.f, 0.f, 0.f}, c1 = {0.f, 0.f, 0.f, 0.f};
  short8 a = __builtin_bit_cast(short8, tkb);
  c0 = __builtin_amdgcn_mfma_f32_16x16x32_bf16(a, B0, c0, 0, 0, 0);
  c1 = __builtin_amdgcn_mfma_f32_16x16x32_bf16(a, B1, c1, 0, 0, 0);

  int br = (lane >> 4) * 4;
#pragma unroll
  for (int r = 0; r < 4; ++r) {
    size_t o = ((size_t)(br + r) * NND + n) * NFOUT + fo;
    out[o]      += c0[r];
    out[o + 16] += c1[r];
  }
}

// ---------------- launch ----------------
static inline size_t alignup(size_t v) { return (v + 255) & ~(size_t)255; }

extern "C" void kernel_launch(void* const* d_in, const int* in_sizes, int n_in,
                              void* d_out, int out_size, void* d_ws, size_t ws_size,
                              hipStream_t stream) {
  const float* x    = (const float*)d_in[0];
  const int*   rows = (const int*)d_in[1];
  const int*   cols = (const int*)d_in[2];
  const float* vals = (const float*)d_in[3];
  const float* W    = (const float*)d_in[4];
  float* out = (float*)d_out;

  const size_t tbytes   = alignup((size_t)NND * DDIM * 2);       // one T level
  const size_t csrbytes = 4 * alignup((size_t)(NND + 1) * 4)
                        + 2 * alignup((size_t)NNZE * 4);
  const size_t deferred_need = (size_t)NCHEB * tbytes + alignup(12 * 64 * 8 * 2) + csrbytes;

  const int grid = NND / 4;   // 12500 blocks x 256 threads, one wave per node
  const int nscan = (NND + 1023) / 1024;   // 49

  if (ws_size >= deferred_need) {
    // ---------- deferred-epilogue path ----------
    char* p = (char*)d_ws;
    size_t off = 0;
    unsigned short* Tall  = (unsigned short*)(p + off); off += (size_t)NCHEB * tbytes;
    unsigned short* Wfrag = (unsigned short*)(p + off); off += alignup(12 * 64 * 8 * 2);
    int*   cnt      = (int*)(p + off); off += alignup((size_t)(NND + 1) * 4);
    int*   rowptr   = (int*)(p + off); off += alignup((size_t)(NND + 1) * 4);
    int*   cursor   = (int*)(p + off); off += alignup((size_t)(NND + 1) * 4);
    int*   partials = (int*)(p + off); off += alignup((size_t)(NND + 1) * 4);
    int*   ccol     = (int*)(p + off); off += alignup((size_t)NNZE * 4);
    float* cval     = (float*)(p + off); off += alignup((size_t)NNZE * 4);

    hipMemsetAsync(cnt, 0, (size_t)NND * 4, stream);
    hist_kernel<<<(NNZE + 255) / 256, 256, 0, stream>>>(rows, cnt, NNZE);
    scanA_kernel<<<nscan, 1024, 0, stream>>>(cnt, rowptr, partials, NND);
    scanB_kernel<<<1, 1, 0, stream>>>(partials, nscan);
    scanC_kernel<<<nscan, 1024, 0, stream>>>(partials, rowptr, cursor, NND);
    fill_kernel<<<(NNZE + 255) / 256, 256, 0, stream>>>(rows, cols, vals, cursor, ccol, cval, NNZE);
    wprep_kernel<<<3, 256, 0, stream>>>(W, Wfrag);

    auto Tk = [&](int k) { return Tall + (size_t)k * NND * DDIM; };

    cheb_k0_nf<<<grid, 256, 0, stream>>>(x, Tk(0));
    cheb_level_v3<<<grid, 256, 0, stream>>>(Tk(0), nullptr, Tk(1), rowptr, ccol, cval, 1.f, 0.f);
    cheb_level_v3<<<grid, 256, 0, stream>>>(Tk(1), Tk(0), Tk(2), rowptr, ccol, cval, 2.f, 1.f);
    cheb_level_v3<<<grid, 256, 0, stream>>>(Tk(2), Tk(1), Tk(3), rowptr, ccol, cval, 2.f, 1.f);
    cheb_level_v3<<<grid, 256, 0, stream>>>(Tk(3), Tk(2), Tk(4), rowptr, ccol, cval, 2.f, 1.f);
    cheb_level5_epi<<<grid, 256, 0, stream>>>(Tk(4), Tk(3), Tall, Wfrag, rowptr, ccol, cval, out);
  } else {
    // ---------- fallback: fused epilogue, 2 T buffers ----------
    char* p = (char*)d_ws;
    size_t off = 0;
    unsigned short* bufA = (unsigned short*)(p + off); off += tbytes;
    unsigned short* bufB = (unsigned short*)(p + off); off += tbytes;
    int*   cnt    = (int*)(p + off); off += alignup((size_t)(NND + 1) * 4);
    int*   rowptr = (int*)(p + off); off += alignup((size_t)(NND + 1) * 4);
    int*   cursor = (int*)(p + off); off += alignup((size_t)(NND + 1) * 4);
    int*   ccol   = (int*)(p + off); off += alignup((size_t)NNZE * 4);
    float* cval   = (float*)(p + off); off += alignup((size_t)NNZE * 4);

    hipMemsetAsync(cnt, 0, (size_t)NND * 4, stream);
    hist_kernel<<<(NNZE + 255) / 256, 256, 0, stream>>>(rows, cnt, NNZE);
    scan_kernel<<<1, 1024, 0, stream>>>(cnt, rowptr, cursor, NND);
    fill_kernel<<<(NNZE + 255) / 256, 256, 0, stream>>>(rows, cols, vals, cursor, ccol, cval, NNZE);

    cheb_k0_fused<<<grid, 256, 0, stream>>>(x, bufA, W, out);
    cheb_level_fused<<<grid, 256, 0, stream>>>(bufA, bufB, rowptr, ccol, cval, W, out, 1, 1.f, 0.f, 1);
    cheb_level_fused<<<grid, 256, 0, stream>>>(bufB, bufA, rowptr, ccol, cval, W, out, 2, 2.f, 1.f, 1);
    cheb_level_fused<<<grid, 256, 0, stream>>>(bufA, bufB, rowptr, ccol, cval, W, out, 3, 2.f, 1.f, 1);
    cheb_level_fused<<<grid, 256, 0, stream>>>(bufB, bufA, rowptr, ccol, cval, W, out, 4, 2.f, 1.f, 1);
    cheb_level_fused<<<grid, 256, 0, stream>>>(bufA, bufB, rowptr, ccol, cval, W, out, 5, 2.f, 1.f, 0);
  }
}

// Round 4
// 552.511 us; speedup vs baseline: 1.7187x; 1.4220x over previous
//
#include <hip/hip_runtime.h>
#include <hip/hip_bf16.h>

// Problem constants (cheb_conv): B=16, N=50000, FIN=32, FOUT=32, K=6, NNZ=800000
#define NND   50000
#define NBATCH 16
#define NFIN  32
#define NFOUT 32
#define NCHEB 6
#define NNZE  800000
#define DDIM  512   // NBATCH*NFIN

typedef __attribute__((ext_vector_type(8))) short    short8;
typedef __attribute__((ext_vector_type(8))) unsigned short u16x8;
typedef __attribute__((ext_vector_type(4))) float    f32x4;
typedef __attribute__((ext_vector_type(2))) float    f32x2;

__device__ __forceinline__ float b2f(unsigned short u) {
  union { unsigned u; float f; } v; v.u = ((unsigned)u) << 16; return v.f;
}
__device__ __forceinline__ unsigned short f2bf(float f) {
  union { float f; unsigned u; } v; v.f = f;
  unsigned r = v.u + 0x7fffu + ((v.u >> 16) & 1u);   // RNE
  return (unsigned short)(r >> 16);
}
// f32 -> OCP e4m3fn byte, software RNE (hardware cvt rounding mode not trusted)
__device__ __forceinline__ unsigned f2fp8(float f) {
  unsigned s = (__float_as_uint(f) >> 24) & 0x80u;
  float af = fminf(fabsf(f), 448.0f);
  unsigned b;
  if (af < 0.015625f) {                       // subnormal region: linear code 0..8
    b = (unsigned)__float2int_rn(af * 512.0f);
  } else {
    unsigned u = __float_as_uint(af);
    u += 0x7FFFFu + ((u >> 20) & 1u);         // RNE into 3-bit mantissa
    b = (((u >> 23) - 120u) << 3) | ((u >> 20) & 7u);
    if (b > 0x7Eu) b = 0x7Eu;                 // clamp at 448, avoid NaN code
  }
  return s | b;
}

// ---------------- CSR build ----------------
__global__ void hist_kernel(const int* __restrict__ rows, int* __restrict__ cnt, int nnz) {
  int e = blockIdx.x * blockDim.x + threadIdx.x;
  if (e < nnz) atomicAdd(&cnt[rows[e]], 1);
}

__global__ __launch_bounds__(1024) void scanA_kernel(const int* __restrict__ cnt,
                                                     int* __restrict__ rowptr,
                                                     int* __restrict__ partials, int n) {
  __shared__ int lds[1024];
  int b = blockIdx.x, tid = threadIdx.x, i = b * 1024 + tid;
  int v = (i < n) ? cnt[i] : 0;
  lds[tid] = v;
  __syncthreads();
  int s = v;
  for (int off = 1; off < 1024; off <<= 1) {
    int t = (tid >= off) ? lds[tid - off] : 0;
    __syncthreads();
    s += t;
    lds[tid] = s;
    __syncthreads();
  }
  if (i < n) rowptr[i] = s - v;
  if (tid == 1023) partials[b] = s;
}

// merged: thread 0 = serial partial-scan; threads 64..831 = W -> MFMA B-frag pack
__global__ void scanB_wprep(int* __restrict__ partials, int nb,
                            const float* __restrict__ W, unsigned short* __restrict__ Wfrag) {
  int t = threadIdx.x;
  if (t == 0) {
    int run = 0;
    for (int b = 0; b < nb; ++b) { int x = partials[b]; partials[b] = run; run += x; }
  } else if (t >= 64 && t < 64 + 768) {
    int w = t - 64;
    int frag = w >> 6, lane = w & 63;
    int kk = frag >> 1, h = frag & 1;
    int fo = (lane & 15) + h * 16, kc = (lane >> 4) * 8;
    u16x8 b;
#pragma unroll
    for (int j = 0; j < 8; ++j)
      b[j] = f2bf(W[((size_t)(kc + j) * NCHEB + kk) * NFOUT + fo]);
    *(u16x8*)(Wfrag + (size_t)w * 8) = b;
  }
}

__global__ __launch_bounds__(1024) void scanC_kernel(const int* __restrict__ partials,
                                                     int* __restrict__ rowptr,
                                                     int* __restrict__ cursor, int n) {
  int i = blockIdx.x * 1024 + threadIdx.x;
  if (i < n) {
    int r = rowptr[i] + partials[blockIdx.x];
    rowptr[i] = r;
    cursor[i] = r;
  }
  if (i == n) rowptr[n] = NNZE;
}

// packed edges: ecv[p] = (col in low 32) | (val bits in high 32)
__global__ void fill_kernel(const int* __restrict__ rows, const int* __restrict__ cols,
                            const float* __restrict__ vals, int* __restrict__ cursor,
                            long* __restrict__ ecv, int nnz) {
  int e = blockIdx.x * blockDim.x + threadIdx.x;
  if (e < nnz) {
    int r = rows[e];
    int p = atomicAdd(&cursor[r], 1);
    ecv[p] = (long)((unsigned long long)__float_as_uint(vals[e]) << 32 | (unsigned)cols[e]);
  }
}

// ---------------- Level 0: transpose x -> T0 (bf16, MFMA A-frag order) + fp8 copy ----------------
// T layout per node: pos = lane*8+j <-> (b = lane&15, fi = (lane>>4)*8 + j)
__global__ __launch_bounds__(256) void cheb_k0_q(const float* __restrict__ x,
                                                 unsigned short* __restrict__ T0,
                                                 char* __restrict__ Tq0) {
  int wave = threadIdx.x >> 6, lane = threadIdx.x & 63;
  int n = blockIdx.x * 4 + wave;
  int kc = (lane >> 4) * 8;
  int b  = lane & 15;

  const float* xp = x + ((size_t)b * NND + n) * NFIN + kc;
  float4 xa = *(const float4*)xp;
  float4 xb = *(const float4*)(xp + 4);
  float tv[8] = {xa.x, xa.y, xa.z, xa.w, xb.x, xb.y, xb.z, xb.w};

  u16x8 tb;
#pragma unroll
  for (int j = 0; j < 8; ++j) tb[j] = f2bf(tv[j]);
  *(u16x8*)(T0 + (size_t)n * DDIM + lane * 8) = tb;

  unsigned lo = f2fp8(tv[0]) | (f2fp8(tv[1]) << 8) | (f2fp8(tv[2]) << 16) | (f2fp8(tv[3]) << 24);
  unsigned hi = f2fp8(tv[4]) | (f2fp8(tv[5]) << 8) | (f2fp8(tv[6]) << 16) | (f2fp8(tv[7]) << 24);
  int2 qq; qq.x = (int)lo; qq.y = (int)hi;
  *(int2*)(Tq0 + (size_t)n * 512 + lane * 8) = qq;
}

// ---------------- fp8 gather core: acc += sum_e val[e] * Tq[col[e]] (8-deep MLP) ----------------
__device__ __forceinline__ void gather_q(const char* __restrict__ qbase,  // Tq + lane*8
                                         const long* __restrict__ ecv,
                                         int s, int e1, float acc[8]) {
  int e = s;
  for (; e + 8 <= e1; e += 8) {
    long m[8];
#pragma unroll
    for (int q = 0; q < 8; ++q) m[q] = __builtin_nontemporal_load(ecv + e + q);
    int2 d[8];
#pragma unroll
    for (int q = 0; q < 8; ++q) d[q] = *(const int2*)(qbase + (size_t)(int)m[q] * 512);
#pragma unroll
    for (int q = 0; q < 8; ++q) {
      float v = __int_as_float((int)(m[q] >> 32));
      f32x2 f01 = __builtin_amdgcn_cvt_pk_f32_fp8(d[q].x, false);
      f32x2 f23 = __builtin_amdgcn_cvt_pk_f32_fp8(d[q].x, true);
      f32x2 f45 = __builtin_amdgcn_cvt_pk_f32_fp8(d[q].y, false);
      f32x2 f67 = __builtin_amdgcn_cvt_pk_f32_fp8(d[q].y, true);
      acc[0] = fmaf(v, f01.x, acc[0]);
      acc[1] = fmaf(v, f01.y, acc[1]);
      acc[2] = fmaf(v, f23.x, acc[2]);
      acc[3] = fmaf(v, f23.y, acc[3]);
      acc[4] = fmaf(v, f45.x, acc[4]);
      acc[5] = fmaf(v, f45.y, acc[5]);
      acc[6] = fmaf(v, f67.x, acc[6]);
      acc[7] = fmaf(v, f67.y, acc[7]);
    }
  }
  if (e + 4 <= e1) {
    long m[4];
#pragma unroll
    for (int q = 0; q < 4; ++q) m[q] = __builtin_nontemporal_load(ecv + e + q);
    int2 d[4];
#pragma unroll
    for (int q = 0; q < 4; ++q) d[q] = *(const int2*)(qbase + (size_t)(int)m[q] * 512);
#pragma unroll
    for (int q = 0; q < 4; ++q) {
      float v = __int_as_float((int)(m[q] >> 32));
      f32x2 f01 = __builtin_amdgcn_cvt_pk_f32_fp8(d[q].x, false);
      f32x2 f23 = __builtin_amdgcn_cvt_pk_f32_fp8(d[q].x, true);
      f32x2 f45 = __builtin_amdgcn_cvt_pk_f32_fp8(d[q].y, false);
      f32x2 f67 = __builtin_amdgcn_cvt_pk_f32_fp8(d[q].y, true);
      acc[0] = fmaf(v, f01.x, acc[0]);
      acc[1] = fmaf(v, f01.y, acc[1]);
      acc[2] = fmaf(v, f23.x, acc[2]);
      acc[3] = fmaf(v, f23.y, acc[3]);
      acc[4] = fmaf(v, f45.x, acc[4]);
      acc[5] = fmaf(v, f45.y, acc[5]);
      acc[6] = fmaf(v, f67.x, acc[6]);
      acc[7] = fmaf(v, f67.y, acc[7]);
    }
    e += 4;
  }
  for (; e < e1; ++e) {
    long mm = __builtin_nontemporal_load(ecv + e);
    int2 dd = *(const int2*)(qbase + (size_t)(int)mm * 512);
    float v = __int_as_float((int)(mm >> 32));
    f32x2 f01 = __builtin_amdgcn_cvt_pk_f32_fp8(dd.x, false);
    f32x2 f23 = __builtin_amdgcn_cvt_pk_f32_fp8(dd.x, true);
    f32x2 f45 = __builtin_amdgcn_cvt_pk_f32_fp8(dd.y, false);
    f32x2 f67 = __builtin_amdgcn_cvt_pk_f32_fp8(dd.y, true);
    acc[0] = fmaf(v, f01.x, acc[0]);
    acc[1] = fmaf(v, f01.y, acc[1]);
    acc[2] = fmaf(v, f23.x, acc[2]);
    acc[3] = fmaf(v, f23.y, acc[3]);
    acc[4] = fmaf(v, f45.x, acc[4]);
    acc[5] = fmaf(v, f45.y, acc[5]);
    acc[6] = fmaf(v, f67.x, acc[6]);
    acc[7] = fmaf(v, f67.y, acc[7]);
  }
}

// ---------------- Levels 1..4: T_k = alpha*spmm_q(Tq_{k-1}) - beta*T_{k-2}; write bf16 + fp8 ----------------
__global__ __launch_bounds__(256) void cheb_level_q(const char* __restrict__ Tqprev,
                                                    const unsigned short* __restrict__ Tpp,
                                                    unsigned short* __restrict__ Tdst,
                                                    char* __restrict__ Tqdst,
                                                    const int* __restrict__ rowptr,
                                                    const long* __restrict__ ecv,
                                                    float alpha, float beta) {
  int wave = threadIdx.x >> 6, lane = threadIdx.x & 63;
  int n = blockIdx.x * 4 + wave;
  int s = rowptr[n], e1 = rowptr[n + 1];
  size_t rowoff = (size_t)n * DDIM + lane * 8;

  u16x8 tp2 = {};                              // early independent load
  if (beta != 0.f) tp2 = *(const u16x8*)(Tpp + rowoff);

  float acc[8] = {0.f, 0.f, 0.f, 0.f, 0.f, 0.f, 0.f, 0.f};
  gather_q(Tqprev + (size_t)lane * 8, ecv, s, e1, acc);

  float tk[8];
  if (beta != 0.f) {
#pragma unroll
    for (int j = 0; j < 8; ++j) tk[j] = alpha * acc[j] - beta * b2f(tp2[j]);
  } else {
#pragma unroll
    for (int j = 0; j < 8; ++j) tk[j] = alpha * acc[j];
  }

  u16x8 tkb;
#pragma unroll
  for (int j = 0; j < 8; ++j) tkb[j] = f2bf(tk[j]);
  *(u16x8*)(Tdst + rowoff) = tkb;

  unsigned lo = f2fp8(tk[0]) | (f2fp8(tk[1]) << 8) | (f2fp8(tk[2]) << 16) | (f2fp8(tk[3]) << 24);
  unsigned hi = f2fp8(tk[4]) | (f2fp8(tk[5]) << 8) | (f2fp8(tk[6]) << 16) | (f2fp8(tk[7]) << 24);
  int2 qq; qq.x = (int)lo; qq.y = (int)hi;
  *(int2*)(Tqdst + (size_t)n * 512 + lane * 8) = qq;
}

// ---------------- Level 5 fused with epilogue ----------------
__global__ __launch_bounds__(256) void cheb_level5_epi_q(const char* __restrict__ Tq4,
                                                         const unsigned short* __restrict__ Tall,
                                                         const unsigned short* __restrict__ Wfrag,
                                                         const int* __restrict__ rowptr,
                                                         const long* __restrict__ ecv,
                                                         float* __restrict__ out) {
  int wave = threadIdx.x >> 6, lane = threadIdx.x & 63;
  int n = blockIdx.x * 4 + wave;
  int s = rowptr[n], e1 = rowptr[n + 1];
  size_t rowoff = (size_t)n * DDIM + lane * 8;

  float acc[8] = {0.f, 0.f, 0.f, 0.f, 0.f, 0.f, 0.f, 0.f};
  gather_q(Tq4 + (size_t)lane * 8, ecv, s, e1, acc);

  short8 a[5];
#pragma unroll
  for (int kk = 0; kk < 5; ++kk)
    a[kk] = *(const short8*)(Tall + (size_t)kk * NND * DDIM + rowoff);

  u16x8 tp2 = __builtin_bit_cast(u16x8, a[3]);   // T3 doubles as T_{k-2}
  u16x8 t5b;
#pragma unroll
  for (int j = 0; j < 8; ++j) t5b[j] = f2bf(2.f * acc[j] - b2f(tp2[j]));

  int fo = lane & 15;
  f32x4 c0 = {0.f, 0.f, 0.f, 0.f}, c1 = {0.f, 0.f, 0.f, 0.f};
#pragma unroll
  for (int kk = 0; kk < 5; ++kk) {
    short8 B0 = *(const short8*)(Wfrag + ((size_t)(kk * 2 + 0) * 64 + lane) * 8);
    short8 B1 = *(const short8*)(Wfrag + ((size_t)(kk * 2 + 1) * 64 + lane) * 8);
    c0 = __builtin_amdgcn_mfma_f32_16x16x32_bf16(a[kk], B0, c0, 0, 0, 0);
    c1 = __builtin_amdgcn_mfma_f32_16x16x32_bf16(a[kk], B1, c1, 0, 0, 0);
  }
  {
    short8 a5 = __builtin_bit_cast(short8, t5b);
    short8 B0 = *(const short8*)(Wfrag + ((size_t)(5 * 2 + 0) * 64 + lane) * 8);
    short8 B1 = *(const short8*)(Wfrag + ((size_t)(5 * 2 + 1) * 64 + lane) * 8);
    c0 = __builtin_amdgcn_mfma_f32_16x16x32_bf16(a5, B0, c0, 0, 0, 0);
    c1 = __builtin_amdgcn_mfma_f32_16x16x32_bf16(a5, B1, c1, 0, 0, 0);
  }

  int br = (lane >> 4) * 4;
#pragma unroll
  for (int r = 0; r < 4; ++r) {
    size_t o = ((size_t)(br + r) * NND + n) * NFOUT + fo;
    out[o]      = c0[r];
    out[o + 16] = c1[r];
  }
}

// ================= Fallback (bf16 fused epilogue, 2-buffer ping-pong) =================
__device__ __forceinline__ void gather_row(const unsigned short* __restrict__ gbase,
                                           const int* __restrict__ ccol,
                                           const float* __restrict__ cval,
                                           int s, int e1, float acc[8]) {
  int e = s;
  for (; e + 4 <= e1; e += 4) {
    int c[4]; float v[4];
#pragma unroll
    for (int q = 0; q < 4; ++q) {
      c[q] = __builtin_nontemporal_load(ccol + e + q);
      v[q] = __builtin_nontemporal_load(cval + e + q);
    }
    u16x8 t[4];
#pragma unroll
    for (int q = 0; q < 4; ++q) t[q] = *(const u16x8*)(gbase + (size_t)c[q] * DDIM);
#pragma unroll
    for (int q = 0; q < 4; ++q)
#pragma unroll
      for (int j = 0; j < 8; ++j) acc[j] = fmaf(v[q], b2f(t[q][j]), acc[j]);
  }
  for (; e < e1; ++e) {
    int   ci = __builtin_nontemporal_load(ccol + e);
    float vi = __builtin_nontemporal_load(cval + e);
    u16x8 ti = *(const u16x8*)(gbase + (size_t)ci * DDIM);
#pragma unroll
    for (int j = 0; j < 8; ++j) acc[j] = fmaf(vi, b2f(ti[j]), acc[j]);
  }
}

__global__ void scan_kernel(const int* __restrict__ cnt, int* __restrict__ rowptr,
                            int* __restrict__ cursor, int n) {
  __shared__ int lds[1024];
  int tid = threadIdx.x;
  int run = 0;
  for (int base = 0; base <= n; base += 1024) {
    int i = base + tid;
    int v = (i < n) ? cnt[i] : 0;
    lds[tid] = v;
    __syncthreads();
    int s = v;
    for (int off = 1; off < 1024; off <<= 1) {
      int t = (tid >= off) ? lds[tid - off] : 0;
      __syncthreads();
      s += t;
      lds[tid] = s;
      __syncthreads();
    }
    int excl = run + s - v;
    if (i <= n) {
      rowptr[i] = excl;
      if (i < n) cursor[i] = excl;
    }
    run += lds[1023];
    __syncthreads();
  }
}

__global__ void fill2_kernel(const int* __restrict__ rows, const int* __restrict__ cols,
                             const float* __restrict__ vals, int* __restrict__ cursor,
                             int* __restrict__ ccol, float* __restrict__ cval, int nnz) {
  int e = blockIdx.x * blockDim.x + threadIdx.x;
  if (e < nnz) {
    int r = rows[e];
    int p = atomicAdd(&cursor[r], 1);
    ccol[p] = cols[e];
    cval[p] = vals[e];
  }
}

__global__ __launch_bounds__(256) void cheb_k0_fused(const float* __restrict__ x,
                                                     unsigned short* __restrict__ T0,
                                                     const float* __restrict__ W,
                                                     float* __restrict__ out) {
  int wave = threadIdx.x >> 6, lane = threadIdx.x & 63;
  int n = blockIdx.x * 4 + wave;
  int fo = lane & 15, kc = (lane >> 4) * 8;
  int b  = lane & 15;

  const float* xp = x + ((size_t)b * NND + n) * NFIN + kc;
  float4 xa = *(const float4*)xp;
  float4 xb = *(const float4*)(xp + 4);
  float tv[8] = {xa.x, xa.y, xa.z, xa.w, xb.x, xb.y, xb.z, xb.w};

  u16x8 tb;
#pragma unroll
  for (int j = 0; j < 8; ++j) tb[j] = f2bf(tv[j]);
  *(u16x8*)(T0 + (size_t)n * DDIM + lane * 8) = tb;

  short8 B0, B1;
#pragma unroll
  for (int j = 0; j < 8; ++j) {
    int fi = kc + j;
    const float* wp = W + ((size_t)fi * NCHEB + 0) * NFOUT + fo;
    B0[j] = (short)f2bf(wp[0]);
    B1[j] = (short)f2bf(wp[16]);
  }
  f32x4 c0 = {0.f, 0.f, 0.f, 0.f}, c1 = {0.f, 0.f, 0.f, 0.f};
  short8 a = __builtin_bit_cast(short8, tb);
  c0 = __builtin_amdgcn_mfma_f32_16x16x32_bf16(a, B0, c0, 0, 0, 0);
  c1 = __builtin_amdgcn_mfma_f32_16x16x32_bf16(a, B1, c1, 0, 0, 0);

  int br = (lane >> 4) * 4;
#pragma unroll
  for (int r = 0; r < 4; ++r) {
    size_t o = ((size_t)(br + r) * NND + n) * NFOUT + fo;
    out[o]      = c0[r];
    out[o + 16] = c1[r];
  }
}

__global__ __launch_bounds__(256) void cheb_level_fused(const unsigned short* __restrict__ Tprev,
                                                        unsigned short* __restrict__ Tio,
                                                        const int* __restrict__ rowptr,
                                                        const int* __restrict__ ccol,
                                                        const float* __restrict__ cval,
                                                        const float* __restrict__ W,
                                                        float* __restrict__ out,
                                                        int kk, float alpha, float beta, int writeT) {
  int wave = threadIdx.x >> 6, lane = threadIdx.x & 63;
  int n = blockIdx.x * 4 + wave;
  int fo = lane & 15, kc = (lane >> 4) * 8;

  short8 B0, B1;
#pragma unroll
  for (int j = 0; j < 8; ++j) {
    int fi = kc + j;
    const float* wp = W + ((size_t)fi * NCHEB + kk) * NFOUT + fo;
    B0[j] = (short)f2bf(wp[0]);
    B1[j] = (short)f2bf(wp[16]);
  }

  float acc[8] = {0.f, 0.f, 0.f, 0.f, 0.f, 0.f, 0.f, 0.f};
  int s = rowptr[n], e1 = rowptr[n + 1];
  gather_row(Tprev + lane * 8, ccol, cval, s, e1, acc);

  unsigned short* iop = Tio + (size_t)n * DDIM + lane * 8;
  float tk[8];
  if (beta != 0.f) {
    u16x8 tp2 = *(const u16x8*)iop;
#pragma unroll
    for (int j = 0; j < 8; ++j) tk[j] = alpha * acc[j] - beta * b2f(tp2[j]);
  } else {
#pragma unroll
    for (int j = 0; j < 8; ++j) tk[j] = alpha * acc[j];
  }

  u16x8 tkb;
#pragma unroll
  for (int j = 0; j < 8; ++j) tkb[j] = f2bf(tk[j]);
  if (writeT) *(u16x8*)iop = tkb;

  f32x4 c0 = {0.f, 0.f, 0.f, 0.f}, c1 = {0.f, 0.f, 0.f, 0.f};
  short8 a = __builtin_bit_cast(short8, tkb);
  c0 = __builtin_amdgcn_mfma_f32_16x16x32_bf16(a, B0, c0, 0, 0, 0);
  c1 = __builtin_amdgcn_mfma_f32_16x16x32_bf16(a, B1, c1, 0, 0, 0);

  int br = (lane >> 4) * 4;
#pragma unroll
  for (int r = 0; r < 4; ++r) {
    size_t o = ((size_t)(br + r) * NND + n) * NFOUT + fo;
    out[o]      += c0[r];
    out[o + 16] += c1[r];
  }
}

// ---------------- launch ----------------
static inline size_t alignup(size_t v) { return (v + 255) & ~(size_t)255; }

extern "C" void kernel_launch(void* const* d_in, const int* in_sizes, int n_in,
                              void* d_out, int out_size, void* d_ws, size_t ws_size,
                              hipStream_t stream) {
  const float* x    = (const float*)d_in[0];
  const int*   rows = (const int*)d_in[1];
  const int*   cols = (const int*)d_in[2];
  const float* vals = (const float*)d_in[3];
  const float* W    = (const float*)d_in[4];
  float* out = (float*)d_out;

  const size_t tbytes = alignup((size_t)NND * DDIM * 2);     // one bf16 T level (51.2 MB)
  const size_t qbytes = alignup((size_t)NND * 512);          // one fp8 T level (25.6 MB)
  const size_t small  = alignup((size_t)(NND + 1) * 4);
  const size_t need_q = 5 * tbytes + 2 * qbytes + alignup(12 * 64 * 8 * 2)
                      + 4 * small + alignup((size_t)NNZE * 8);

  const int grid  = NND / 4;                 // 12500 blocks x 256 threads, one wave/node
  const int nscan = (NND + 1023) / 1024;     // 49

  if (ws_size >= need_q) {
    // ---------- fp8-gather deferred path ----------
    char* p = (char*)d_ws;
    size_t off = 0;
    unsigned short* Tall  = (unsigned short*)(p + off); off += 5 * tbytes;   // T0..T4 bf16
    char* bufQA = (char*)(p + off); off += qbytes;
    char* bufQB = (char*)(p + off); off += qbytes;
    unsigned short* Wfrag = (unsigned short*)(p + off); off += alignup(12 * 64 * 8 * 2);
    int*  cnt      = (int*)(p + off); off += small;
    int*  rowptr   = (int*)(p + off); off += small;
    int*  cursor   = (int*)(p + off); off += small;
    int*  partials = (int*)(p + off); off += small;
    long* ecv      = (long*)(p + off); off += alignup((size_t)NNZE * 8);

    hipMemsetAsync(cnt, 0, (size_t)NND * 4, stream);
    hist_kernel<<<(NNZE + 255) / 256, 256, 0, stream>>>(rows, cnt, NNZE);
    scanA_kernel<<<nscan, 1024, 0, stream>>>(cnt, rowptr, partials, NND);
    scanB_wprep<<<1, 832, 0, stream>>>(partials, nscan, W, Wfrag);
    scanC_kernel<<<nscan, 1024, 0, stream>>>(partials, rowptr, cursor, NND);
    fill_kernel<<<(NNZE + 255) / 256, 256, 0, stream>>>(rows, cols, vals, cursor, ecv, NNZE);

    auto Tk = [&](int k) { return Tall + (size_t)k * NND * DDIM; };

    cheb_k0_q<<<grid, 256, 0, stream>>>(x, Tk(0), bufQA);
    cheb_level_q<<<grid, 256, 0, stream>>>(bufQA, nullptr, Tk(1), bufQB, rowptr, ecv, 1.f, 0.f);
    cheb_level_q<<<grid, 256, 0, stream>>>(bufQB, Tk(0), Tk(2), bufQA, rowptr, ecv, 2.f, 1.f);
    cheb_level_q<<<grid, 256, 0, stream>>>(bufQA, Tk(1), Tk(3), bufQB, rowptr, ecv, 2.f, 1.f);
    cheb_level_q<<<grid, 256, 0, stream>>>(bufQB, Tk(2), Tk(4), bufQA, rowptr, ecv, 2.f, 1.f);
    cheb_level5_epi_q<<<grid, 256, 0, stream>>>(bufQA, Tall, Wfrag, rowptr, ecv, out);
  } else {
    // ---------- fallback: bf16 fused epilogue, 2 T buffers ----------
    char* p = (char*)d_ws;
    size_t off = 0;
    unsigned short* bufA = (unsigned short*)(p + off); off += tbytes;
    unsigned short* bufB = (unsigned short*)(p + off); off += tbytes;
    int*   cnt    = (int*)(p + off); off += small;
    int*   rowptr = (int*)(p + off); off += small;
    int*   cursor = (int*)(p + off); off += small;
    int*   ccol   = (int*)(p + off); off += alignup((size_t)NNZE * 4);
    float* cval   = (float*)(p + off); off += alignup((size_t)NNZE * 4);

    hipMemsetAsync(cnt, 0, (size_t)NND * 4, stream);
    hist_kernel<<<(NNZE + 255) / 256, 256, 0, stream>>>(rows, cnt, NNZE);
    scan_kernel<<<1, 1024, 0, stream>>>(cnt, rowptr, cursor, NND);
    fill2_kernel<<<(NNZE + 255) / 256, 256, 0, stream>>>(rows, cols, vals, cursor, ccol, cval, NNZE);

    cheb_k0_fused<<<grid, 256, 0, stream>>>(x, bufA, W, out);
    cheb_level_fused<<<grid, 256, 0, stream>>>(bufA, bufB, rowptr, ccol, cval, W, out, 1, 1.f, 0.f, 1);
    cheb_level_fused<<<grid, 256, 0, stream>>>(bufB, bufA, rowptr, ccol, cval, W, out, 2, 2.f, 1.f, 1);
    cheb_level_fused<<<grid, 256, 0, stream>>>(bufA, bufB, rowptr, ccol, cval, W, out, 3, 2.f, 1.f, 1);
    cheb_level_fused<<<grid, 256, 0, stream>>>(bufB, bufA, rowptr, ccol, cval, W, out, 4, 2.f, 1.f, 1);
    cheb_level_fused<<<grid, 256, 0, stream>>>(bufA, bufB, rowptr, ccol, cval, W, out, 5, 2.f, 1.f, 0);
  }
}